// Round 1
// baseline (1453.853 us; speedup 1.0000x reference)
//
#include <hip/hip_runtime.h>

// ---------------------------------------------------------------------------
// STEncoder (STGCN-style) on MI355X.
// Shapes: B=16, N=2000 (pad 2048), T=12, D_IN=3, C=64, CM=32, KS=KT=3.
// Pipeline per block: GLU tconv -> (Y1=X L^T, Y2=Y1 L^T bf16 MFMA GEMMs)
//                     -> theta mix (+relu, resid) -> relu tconv -> LayerNorm.
// Chebyshev trick: T0=I, T2=2L^2-I  => only 2 GEMMs per block; k=0/k=2 terms
// folded into the 32x32 channel mix (th_a = th0-th2, th_2' = 2*th2).
// All activations bf16; fp32 accumulation everywhere.
// ---------------------------------------------------------------------------

typedef unsigned short u16;
typedef __attribute__((ext_vector_type(8))) short short8;   // 8 x bf16 frag
typedef __attribute__((ext_vector_type(4))) float floatx4;  // MFMA acc

struct __attribute__((aligned(8))) us4 { u16 x, y, z, w; };

#define AS1 __attribute__((address_space(1)))
#define AS3 __attribute__((address_space(3)))

__device__ __forceinline__ float b2f(u16 h) {
  union { unsigned int u; float f; } v;
  v.u = ((unsigned int)h) << 16;
  return v.f;
}
__device__ __forceinline__ u16 f2b(float f) {
  union { float f; unsigned int u; } v;
  v.f = f;
  unsigned int r = (v.u + 0x7fffu + ((v.u >> 16) & 1u)) >> 16;
  return (u16)r;
}
__device__ __forceinline__ void gl_lds16(const u16* g, u16* l) {
  // async global->LDS, 16B per lane; LDS dest = wave-uniform base + lane*16
  __builtin_amdgcn_global_load_lds((const AS1 unsigned int*)g,
                                   (AS3 unsigned int*)l, 16, 0, 0);
}

// guarded 4x bf16 row load (row extent 2000), zeros beyond
__device__ __forceinline__ us4 load4_guard(const u16* gp, int n) {
  if (n + 3 < 2000) return *(const us4*)gp;
  us4 r;
  r.x = (n + 0 < 2000) ? gp[0] : (u16)0;
  r.y = (n + 1 < 2000) ? gp[1] : (u16)0;
  r.z = (n + 2 < 2000) ? gp[2] : (u16)0;
  r.w = (n + 3 < 2000) ? gp[3] : (u16)0;
  return r;
}

// --------------------------- graph preprocessing ---------------------------

// d[n] = (sum_m (graph[n,m]) + 1)^(-1/2)   (clip 1e-6; diag of g=graph+I)
__global__ void k_deg(const float* __restrict__ graph, float* __restrict__ d) {
  const int n = blockIdx.x;
  const int tid = threadIdx.x;
  float s = 0.f;
  const float* row = graph + (size_t)n * 2000;
  for (int m = tid; m < 2000; m += 256) s += row[m];
  __shared__ float red[256];
  red[tid] = s;
  __syncthreads();
  for (int st = 128; st > 0; st >>= 1) {
    if (tid < st) red[tid] += red[tid + st];
    __syncthreads();
  }
  if (tid == 0) d[n] = rsqrtf(fmaxf(red[0] + 1.f, 1e-6f));
}

// L[n,m] = delta - d[n]*(graph[n,m]+delta)*d[m], zero-padded to 2048x2048 bf16
__global__ void k_lap(const float* __restrict__ graph, const float* __restrict__ d,
                      u16* __restrict__ L) {
  const int m = blockIdx.x * 256 + threadIdx.x;  // 0..2047
  const int n = blockIdx.y;                      // 0..2047
  float v = 0.f;
  if (n < 2000 && m < 2000) {
    float delta = (n == m) ? 1.f : 0.f;
    float gg = graph[(size_t)n * 2000 + m] + delta;
    v = delta - d[n] * gg * d[m];
  }
  L[(size_t)n * 2048 + m] = f2b(v);
}

// --------------------------- input 1x1 conv (K=3) ---------------------------

__global__ void k_inconv(const float* __restrict__ x, const float* __restrict__ w,
                         const float* __restrict__ bias, u16* __restrict__ h0) {
  const int n = blockIdx.x * 256 + threadIdx.x;
  const int b = blockIdx.y / 12, t = blockIdx.y % 12;
  if (n >= 2000) return;
  const float x0 = x[((size_t)(b * 3 + 0) * 12 + t) * 2000 + n];
  const float x1 = x[((size_t)(b * 3 + 1) * 12 + t) * 2000 + n];
  const float x2 = x[((size_t)(b * 3 + 2) * 12 + t) * 2000 + n];
  for (int o = 0; o < 64; ++o) {
    float v = x0 * w[o] + x1 * w[64 + o] + x2 * w[128 + o] + bias[o];
    h0[((size_t)(b * 64 + o) * 12 + t) * 2000 + n] = f2b(v);
  }
}

// --------------------------- GLU temporal conv ------------------------------
// in : h   bf16 [B,64,T_in,2000]
// out: Xp  bf16 [B*32*(T_in-2), 2048]  (GEMM A-matrix, zero-padded cols)
__global__ __launch_bounds__(256, 2)
void k_glu(const u16* __restrict__ h, const float* __restrict__ w,
           const float* __restrict__ bias, const float* __restrict__ aw,
           const float* __restrict__ ab, u16* __restrict__ Xp, int T_in) {
  const int T_out = T_in - 2;
  __shared__ u16 hs[192 * 128];   // [k=dt*64+c][n]  49.2 KB
  __shared__ u16 wt[192 * 64];    // [k][o]          24.6 KB
  __shared__ u16 awt[64 * 32];    // [c][i]           4.1 KB
  const int tid = threadIdx.x;
  const int n0 = blockIdx.x * 128;
  const int b = blockIdx.y / T_out;
  const int t = blockIdx.y % T_out;

  for (int idx = tid; idx < 192 * 64; idx += 256) {
    int k = idx >> 6, o = idx & 63;
    int dt = k >> 6, c = k & 63;
    wt[idx] = f2b(w[(size_t)(o * 64 + c) * 3 + dt]);  // t1_w[o][c][dt]
  }
  for (int idx = tid; idx < 64 * 32; idx += 256) {
    int c = idx >> 5, i = idx & 31;
    awt[idx] = f2b(aw[i * 64 + c]);                   // aw[i][c]
  }
  for (int cidx = tid; cidx < 192 * 32; cidx += 256) {
    int r = cidx >> 5, off = (cidx & 31) * 4;
    int dt = r >> 6, c = r & 63;
    const u16* gp = h + (size_t)((b * 64 + c) * T_in + t + dt) * 2000 + n0 + off;
    *(us4*)&hs[r * 128 + off] = load4_guard(gp, n0 + off);
  }
  __syncthreads();

  const int i = tid & 31;
  const int nb = (tid >> 5) * 16;
  float accA[16], accB[16], accI[16];
#pragma unroll
  for (int j = 0; j < 16; ++j) { accA[j] = 0.f; accB[j] = 0.f; accI[j] = 0.f; }

  for (int k = 0; k < 128; ++k) {  // dt = 0,1
    const float wa = b2f(wt[k * 64 + i]);
    const float wb = b2f(wt[k * 64 + 32 + i]);
    const u16* hr = &hs[k * 128 + nb];
#pragma unroll
    for (int jj = 0; jj < 4; ++jj) {
      const us4 hv = *(const us4*)(hr + jj * 4);
      const float v0 = b2f(hv.x), v1 = b2f(hv.y), v2 = b2f(hv.z), v3 = b2f(hv.w);
      accA[jj * 4 + 0] += wa * v0; accB[jj * 4 + 0] += wb * v0;
      accA[jj * 4 + 1] += wa * v1; accB[jj * 4 + 1] += wb * v1;
      accA[jj * 4 + 2] += wa * v2; accB[jj * 4 + 2] += wb * v2;
      accA[jj * 4 + 3] += wa * v3; accB[jj * 4 + 3] += wb * v3;
    }
  }
  for (int k = 128; k < 192; ++k) {  // dt = 2: also the 1x1 align conv
    const float wa = b2f(wt[k * 64 + i]);
    const float wb = b2f(wt[k * 64 + 32 + i]);
    const float wi = b2f(awt[(k - 128) * 32 + i]);
    const u16* hr = &hs[k * 128 + nb];
#pragma unroll
    for (int jj = 0; jj < 4; ++jj) {
      const us4 hv = *(const us4*)(hr + jj * 4);
      const float v0 = b2f(hv.x), v1 = b2f(hv.y), v2 = b2f(hv.z), v3 = b2f(hv.w);
      accA[jj * 4 + 0] += wa * v0; accB[jj * 4 + 0] += wb * v0; accI[jj * 4 + 0] += wi * v0;
      accA[jj * 4 + 1] += wa * v1; accB[jj * 4 + 1] += wb * v1; accI[jj * 4 + 1] += wi * v1;
      accA[jj * 4 + 2] += wa * v2; accB[jj * 4 + 2] += wb * v2; accI[jj * 4 + 2] += wi * v2;
      accA[jj * 4 + 3] += wa * v3; accB[jj * 4 + 3] += wb * v3; accI[jj * 4 + 3] += wi * v3;
    }
  }

  const float bA = bias[i] + ab[i];
  const float bB = bias[32 + i];
  const size_t rbase = (size_t)((b * 32 + i) * T_out + t) * 2048 + n0 + nb;
#pragma unroll
  for (int j = 0; j < 16; ++j) {
    const int n = n0 + nb + j;
    const float sv = accA[j] + accI[j] + bA;
    const float gate = 1.f / (1.f + __expf(-(accB[j] + bB)));
    Xp[rbase + j] = (n < 2000) ? f2b(sv * gate) : (u16)0;  // writes pad zeros too
  }
}

// --------------------------- bf16 MFMA GEMM (C = A * Bt^T) ------------------
// A [M,2048] bf16 row-major, Bt [2048,2048] bf16 row-major, C [M,2048] bf16.
// 128x128 tile, BK=32, 256 threads (4 waves, 2x2 of 64x64), m97 structure.
__global__ __launch_bounds__(256, 2)
void k_gemm(const u16* __restrict__ A, const u16* __restrict__ Bt,
            u16* __restrict__ C) {
  constexpr int K = 2048;
  __shared__ u16 As[128 * 32];
  __shared__ u16 Bs[128 * 32];
  const int tid = threadIdx.x;
  const int lane = tid & 63, wave = tid >> 6;
  const int m0 = blockIdx.y * 128, n0 = blockIdx.x * 128;
  const int wy = wave >> 1, wx = wave & 1;
  const int quad = lane >> 4, l15 = lane & 15;

  // staging: 512 16B-chunks per tile; wave w covers chunks [w*128, w*128+128)
  const int c0 = wave * 128 + lane;
  const int c1 = c0 + 64;
  const u16* Ag0 = A + (size_t)(m0 + (c0 >> 2)) * K + (c0 & 3) * 8;
  const u16* Ag1 = A + (size_t)(m0 + (c1 >> 2)) * K + (c1 & 3) * 8;
  const u16* Bg0 = Bt + (size_t)(n0 + (c0 >> 2)) * K + (c0 & 3) * 8;
  const u16* Bg1 = Bt + (size_t)(n0 + (c1 >> 2)) * K + (c1 & 3) * 8;
  u16* lA0 = &As[(wave * 2 + 0) * 512];
  u16* lA1 = &As[(wave * 2 + 1) * 512];
  u16* lB0 = &Bs[(wave * 2 + 0) * 512];
  u16* lB1 = &Bs[(wave * 2 + 1) * 512];

  floatx4 acc[4][4] = {};

  for (int k0 = 0; k0 < K; k0 += 32) {
    gl_lds16(Ag0 + k0, lA0);
    gl_lds16(Ag1 + k0, lA1);
    gl_lds16(Bg0 + k0, lB0);
    gl_lds16(Bg1 + k0, lB1);
    asm volatile("s_waitcnt vmcnt(0)" ::: "memory");
    __syncthreads();

    short8 af[4], bf[4];
#pragma unroll
    for (int mi = 0; mi < 4; ++mi)
      af[mi] = *(const short8*)&As[(wy * 64 + mi * 16 + l15) * 32 + quad * 8];
#pragma unroll
    for (int ni = 0; ni < 4; ++ni)
      bf[ni] = *(const short8*)&Bs[(wx * 64 + ni * 16 + l15) * 32 + quad * 8];
#pragma unroll
    for (int mi = 0; mi < 4; ++mi)
#pragma unroll
      for (int ni = 0; ni < 4; ++ni)
        acc[mi][ni] = __builtin_amdgcn_mfma_f32_16x16x32_bf16(
            af[mi], bf[ni], acc[mi][ni], 0, 0, 0);
    __syncthreads();
  }

  // C/D layout: col = lane&15, row = quad*4 + reg  (m89/m91-verified)
#pragma unroll
  for (int mi = 0; mi < 4; ++mi) {
#pragma unroll
    for (int ni = 0; ni < 4; ++ni) {
      const int row = m0 + wy * 64 + mi * 16 + quad * 4;
      const int col = n0 + wx * 64 + ni * 16 + l15;
#pragma unroll
      for (int r = 0; r < 4; ++r)
        C[(size_t)(row + r) * K + col] = f2b(acc[mi][ni][r]);
    }
  }
}

// --------------------------- theta channel mix + relu -----------------------
// s[b,o,t,n] = relu( sum_i (th0-th2)[i,o]*X + th1[i,o]*Y1 + 2*th2[i,o]*Y2
//                    + s_bias[o] + X[o] )
__global__ __launch_bounds__(256, 2)
void k_theta(const u16* __restrict__ Xp, const u16* __restrict__ Y1,
             const u16* __restrict__ Y2, const float* __restrict__ theta,
             const float* __restrict__ sbias, u16* __restrict__ out, int T) {
  __shared__ u16 hs[96 * 128];   // rows: 0..31 X, 32..63 Y1, 64..95 Y2
  __shared__ float wt[96 * 32];  // [k][o]
  const int tid = threadIdx.x;
  const int n0 = blockIdx.x * 128;
  const int b = blockIdx.y / T, t = blockIdx.y % T;

  for (int idx = tid; idx < 96 * 32; idx += 256) {
    int k = idx >> 5, o = idx & 31;
    float v;
    if (k < 32)       v = theta[(k * 32 + o) * 3] - theta[(k * 32 + o) * 3 + 2];
    else if (k < 64)  v = theta[((k - 32) * 32 + o) * 3 + 1];
    else              v = 2.f * theta[((k - 64) * 32 + o) * 3 + 2];
    wt[idx] = v;
  }
  for (int cidx = tid; cidx < 96 * 32; cidx += 256) {
    int r = cidx >> 5, off = (cidx & 31) * 4;
    int src = r >> 5, i = r & 31;
    const u16* base = (src == 0) ? Xp : (src == 1 ? Y1 : Y2);
    const u16* gp = base + (size_t)((b * 32 + i) * T + t) * 2048 + n0 + off;
    *(us4*)&hs[r * 128 + off] = *(const us4*)gp;  // padded buffers: no guard
  }
  __syncthreads();

  const int o = tid & 31;
  const int nb = (tid >> 5) * 16;
  float acc[16];
#pragma unroll
  for (int j = 0; j < 16; ++j) acc[j] = 0.f;

  for (int k = 0; k < 96; ++k) {
    const float wv = wt[k * 32 + o];
    const u16* hr = &hs[k * 128 + nb];
#pragma unroll
    for (int jj = 0; jj < 4; ++jj) {
      const us4 hv = *(const us4*)(hr + jj * 4);
      acc[jj * 4 + 0] += wv * b2f(hv.x);
      acc[jj * 4 + 1] += wv * b2f(hv.y);
      acc[jj * 4 + 2] += wv * b2f(hv.z);
      acc[jj * 4 + 3] += wv * b2f(hv.w);
    }
  }
  const float bo = sbias[o];
  const size_t obase = (size_t)((b * 32 + o) * T + t) * 2000 + n0 + nb;
#pragma unroll
  for (int j = 0; j < 16; ++j) {
    const int n = n0 + nb + j;
    if (n < 2000) {
      float v = acc[j] + bo + b2f(hs[o * 128 + nb + j]);  // residual = X row o
      out[obase + j] = f2b(fmaxf(v, 0.f));
    }
  }
}

// --------------------------- ReLU temporal conv -----------------------------
// out[b,o,t,n] = relu( conv(s)[o] + b[o] + (o<32 ? s[b,o,t+2,n] : 0) )
__global__ __launch_bounds__(256, 2)
void k_t2(const u16* __restrict__ s, const float* __restrict__ w,
          const float* __restrict__ bias, u16* __restrict__ out, int T_in) {
  const int T_out = T_in - 2;
  __shared__ u16 hs[96 * 128];  // [k=dt*32+i][n]
  __shared__ u16 wt[96 * 64];   // [k][o]
  const int tid = threadIdx.x;
  const int n0 = blockIdx.x * 128;
  const int b = blockIdx.y / T_out, t = blockIdx.y % T_out;

  for (int idx = tid; idx < 96 * 64; idx += 256) {
    int k = idx >> 6, o = idx & 63;
    int dt = k >> 5, i = k & 31;
    wt[idx] = f2b(w[(size_t)(o * 32 + i) * 3 + dt]);  // t2_w[o][i][dt]
  }
  for (int cidx = tid; cidx < 96 * 32; cidx += 256) {
    int r = cidx >> 5, off = (cidx & 31) * 4;
    int dt = r >> 5, i = r & 31;
    const u16* gp = s + (size_t)((b * 32 + i) * T_in + t + dt) * 2000 + n0 + off;
    *(us4*)&hs[r * 128 + off] = load4_guard(gp, n0 + off);
  }
  __syncthreads();

  const int o = tid & 63;
  const int nb = (tid >> 6) * 32;
  float acc[32];
#pragma unroll
  for (int j = 0; j < 32; ++j) acc[j] = 0.f;

  for (int k = 0; k < 96; ++k) {
    const float wv = b2f(wt[k * 64 + o]);
    const u16* hr = &hs[k * 128 + nb];
#pragma unroll
    for (int jj = 0; jj < 8; ++jj) {
      const us4 hv = *(const us4*)(hr + jj * 4);
      acc[jj * 4 + 0] += wv * b2f(hv.x);
      acc[jj * 4 + 1] += wv * b2f(hv.y);
      acc[jj * 4 + 2] += wv * b2f(hv.z);
      acc[jj * 4 + 3] += wv * b2f(hv.w);
    }
  }
  const float bo = bias[o];
  const size_t obase = (size_t)((b * 64 + o) * T_out + t) * 2000 + n0 + nb;
#pragma unroll
  for (int j = 0; j < 32; ++j) {
    const int n = n0 + nb + j;
    if (n < 2000) {
      float v = acc[j] + bo;
      if (o < 32) v += b2f(hs[(64 + o) * 128 + nb + j]);  // channel-pad residual
      out[obase + j] = f2b(fmaxf(v, 0.f));
    }
  }
}

// --------------------------- LayerNorm --------------------------------------

__global__ void k_lnstats(const u16* __restrict__ h, float* __restrict__ stats, int T) {
  const int bt = blockIdx.x;
  const int b = bt / T, t = bt % T;
  const int tid = threadIdx.x;
  float s = 0.f, ss = 0.f;
  for (int c = 0; c < 64; ++c) {
    const u16* row = h + (size_t)((b * 64 + c) * T + t) * 2000;
    for (int n = tid; n < 2000; n += 256) {
      const float v = b2f(row[n]);
      s += v; ss += v * v;
    }
  }
  __shared__ float r1[256], r2[256];
  r1[tid] = s; r2[tid] = ss;
  __syncthreads();
  for (int st = 128; st > 0; st >>= 1) {
    if (tid < st) { r1[tid] += r1[tid + st]; r2[tid] += r2[tid + st]; }
    __syncthreads();
  }
  if (tid == 0) {
    const float inv = 1.f / 128000.f;
    const float mu = r1[0] * inv;
    const float var = r2[0] * inv - mu * mu;
    stats[bt * 2] = mu;
    stats[bt * 2 + 1] = rsqrtf(var + 1e-5f);
  }
}

__global__ void k_lnapply(u16* __restrict__ h, const float* __restrict__ stats,
                          const float* __restrict__ gw, const float* __restrict__ gb,
                          float* __restrict__ outf, int T, int write_f32) {
  const int n = blockIdx.x * 256 + threadIdx.x;
  int by = blockIdx.y;
  const int t = by % T; by /= T;
  const int c = by & 63;
  const int b = by >> 6;
  if (n >= 2000) return;
  const int bt = b * T + t;
  const float mu = stats[bt * 2], rs = stats[bt * 2 + 1];
  const size_t idx = (size_t)((b * 64 + c) * T + t) * 2000 + n;
  const float v = (b2f(h[idx]) - mu) * rs * gw[n * 64 + c] + gb[n * 64 + c];
  if (write_f32) outf[idx] = v;
  else h[idx] = f2b(v);
}

// --------------------------- launch -----------------------------------------

extern "C" void kernel_launch(void* const* d_in, const int* in_sizes, int n_in,
                              void* d_out, int out_size, void* d_ws, size_t ws_size,
                              hipStream_t stream) {
  const float* x     = (const float*)d_in[0];
  const float* graph = (const float*)d_in[1];
  const float* in_w  = (const float*)d_in[2];
  const float* in_b  = (const float*)d_in[3];

  char* ws = (char*)d_ws;
  size_t off = 0;
  auto alloc = [&](size_t bytes) -> void* {
    void* p = ws + off;
    off += (bytes + 255) & ~(size_t)255;
    return p;
  };
  float* dd    = (float*)alloc(2048 * 4);
  float* stats = (float*)alloc(16 * 12 * 2 * 4);
  u16* L    = (u16*)alloc((size_t)2048 * 2048 * 2);
  u16* h0   = (u16*)alloc((size_t)16 * 64 * 12 * 2000 * 2);
  u16* Xp   = (u16*)alloc((size_t)5120 * 2048 * 2);
  u16* Y1   = (u16*)alloc((size_t)5120 * 2048 * 2);
  u16* Y2   = (u16*)alloc((size_t)5120 * 2048 * 2);
  u16* sbuf = (u16*)alloc((size_t)16 * 32 * 10 * 2000 * 2);
  u16* h1   = (u16*)alloc((size_t)16 * 64 * 8 * 2000 * 2);
  u16* h2   = h0;  // reuse: h0 is dead after block-1 GLU
  if (off > ws_size) return;  // workspace too small; fail visibly

  k_deg<<<dim3(2000), dim3(256), 0, stream>>>(graph, dd);
  k_lap<<<dim3(8, 2048), dim3(256), 0, stream>>>(graph, dd, L);
  k_inconv<<<dim3(8, 192), dim3(256), 0, stream>>>(x, in_w, in_b, h0);

  for (int blk = 0; blk < 2; ++blk) {
    const int base = 4 + blk * 10;
    const float* t1w = (const float*)d_in[base + 0];
    const float* t1b = (const float*)d_in[base + 1];
    const float* aw  = (const float*)d_in[base + 2];
    const float* ab  = (const float*)d_in[base + 3];
    const float* th  = (const float*)d_in[base + 4];
    const float* sb  = (const float*)d_in[base + 5];
    const float* t2w = (const float*)d_in[base + 6];
    const float* t2b = (const float*)d_in[base + 7];
    const float* lng = (const float*)d_in[base + 8];
    const float* lnb = (const float*)d_in[base + 9];

    const int T_in = (blk == 0) ? 12 : 8;
    const int T_g  = T_in - 2;  // 10 / 6
    const int T_o  = T_g - 2;   // 8 / 4
    const u16* hin = (blk == 0) ? h0 : h1;
    u16* hout      = (blk == 0) ? h1 : h2;
    const int M = 16 * 32 * T_g;  // 5120 / 3072

    k_glu<<<dim3(16, 16 * T_g), dim3(256), 0, stream>>>(hin, t1w, t1b, aw, ab, Xp, T_in);
    k_gemm<<<dim3(16, M / 128), dim3(256), 0, stream>>>(Xp, L, Y1);
    k_gemm<<<dim3(16, M / 128), dim3(256), 0, stream>>>(Y1, L, Y2);
    k_theta<<<dim3(16, 16 * T_g), dim3(256), 0, stream>>>(Xp, Y1, Y2, th, sb, sbuf, T_g);
    k_t2<<<dim3(16, 16 * T_o), dim3(256), 0, stream>>>(sbuf, t2w, t2b, hout, T_g);
    k_lnstats<<<dim3(16 * T_o), dim3(256), 0, stream>>>(hout, stats, T_o);
    k_lnapply<<<dim3(8, 16 * 64 * T_o), dim3(256), 0, stream>>>(
        hout, stats, lng, lnb, (float*)d_out, T_o, blk);
  }
}

// Round 2
// 735.138 us; speedup vs baseline: 1.9777x; 1.9777x over previous
//
#include <hip/hip_runtime.h>

// ---------------------------------------------------------------------------
// STEncoder (STGCN-style) on MI355X.
// B=16, N=2000 (pad 2048), T=12, D_IN=3, C=64, CM=32, KS=KT=3.
// GLU/theta/t2 convs are small-M GEMMs -> unified MFMA kernel k_mix with
// frag-packed LDS staging (in-register transpose, 65-chunk pad).
// Chebyshev: T0=I, T2=2L^2-I -> 2 big GEMMs/block, k0/k2 folded into theta.
// ---------------------------------------------------------------------------

typedef unsigned short u16;
typedef __attribute__((ext_vector_type(8))) short short8;   // 8 x bf16 frag
typedef __attribute__((ext_vector_type(4))) float floatx4;  // MFMA acc

struct __attribute__((aligned(8))) us4 { u16 v[4]; };

#define AS1 __attribute__((address_space(1)))
#define AS3 __attribute__((address_space(3)))

__device__ __forceinline__ float b2f(u16 h) {
  union { unsigned int u; float f; } v;
  v.u = ((unsigned int)h) << 16;
  return v.f;
}
__device__ __forceinline__ u16 f2b(float f) {
  union { float f; unsigned int u; } v;
  v.f = f;
  unsigned int r = (v.u + 0x7fffu + ((v.u >> 16) & 1u)) >> 16;
  return (u16)r;
}
__device__ __forceinline__ void gl_lds16(const u16* g, u16* l) {
  __builtin_amdgcn_global_load_lds((const AS1 unsigned int*)g,
                                   (AS3 unsigned int*)l, 16, 0, 0);
}
__device__ __forceinline__ us4 load4_guard(const u16* gp, int n) {
  if (n + 3 < 2000) return *(const us4*)gp;
  us4 r;
#pragma unroll
  for (int i = 0; i < 4; ++i) r.v[i] = (n + i < 2000) ? gp[i] : (u16)0;
  return r;
}

// --------------------------- graph preprocessing ---------------------------

__global__ void k_deg(const float* __restrict__ graph, float* __restrict__ d) {
  const int n = blockIdx.x;
  const int tid = threadIdx.x;
  float s = 0.f;
  const float* row = graph + (size_t)n * 2000;
  for (int m = tid; m < 2000; m += 256) s += row[m];
  __shared__ float red[256];
  red[tid] = s;
  __syncthreads();
  for (int st = 128; st > 0; st >>= 1) {
    if (tid < st) red[tid] += red[tid + st];
    __syncthreads();
  }
  if (tid == 0) d[n] = rsqrtf(fmaxf(red[0] + 1.f, 1e-6f));
}

__global__ void k_lap(const float* __restrict__ graph, const float* __restrict__ d,
                      u16* __restrict__ L) {
  const int m = blockIdx.x * 256 + threadIdx.x;
  const int n = blockIdx.y;
  float v = 0.f;
  if (n < 2000 && m < 2000) {
    float delta = (n == m) ? 1.f : 0.f;
    float gg = graph[(size_t)n * 2000 + m] + delta;
    v = delta - d[n] * gg * d[m];
  }
  L[(size_t)n * 2048 + m] = f2b(v);
}

// --------------------------- input 1x1 conv (K=3) ---------------------------

__global__ void k_inconv(const float* __restrict__ x, const float* __restrict__ w,
                         const float* __restrict__ bias, u16* __restrict__ h0) {
  const int n = blockIdx.x * 256 + threadIdx.x;
  const int b = blockIdx.y / 12, t = blockIdx.y % 12;
  if (n >= 2000) return;
  const float x0 = x[((size_t)(b * 3 + 0) * 12 + t) * 2000 + n];
  const float x1 = x[((size_t)(b * 3 + 1) * 12 + t) * 2000 + n];
  const float x2 = x[((size_t)(b * 3 + 2) * 12 + t) * 2000 + n];
  for (int o = 0; o < 64; ++o) {
    float v = x0 * w[o] + x1 * w[64 + o] + x2 * w[128 + o] + bias[o];
    h0[((size_t)(b * 64 + o) * 12 + t) * 2000 + n] = f2b(v);
  }
}

// --------------------------- weight fragment packing ------------------------
// Packs weights into MFMA A-frag order: elem (o,k) -> chunk=(mi*KS+ks)*64+
// quad*16+(o&15), j=k&7 (chunk=16B). GLU folds align-conv; theta folds T0/T2.
__global__ void k_wpack(const float* __restrict__ t1w, const float* __restrict__ aw,
                        const float* __restrict__ th, const float* __restrict__ t2w,
                        u16* __restrict__ wglu, u16* __restrict__ wth,
                        u16* __restrict__ wt2) {
  const int mode = blockIdx.x;
  const int tid = threadIdx.x;
  if (mode == 0) {  // GLU: M=64, K=192, KS=6
    for (int idx = tid; idx < 1536 * 8; idx += 256) {
      int chunk = idx >> 3, j = idx & 7;
      int l15 = chunk & 15, quad = (chunk >> 4) & 3, g = chunk >> 6;
      int ks = g % 6, mi = g / 6;
      int o = mi * 16 + l15;
      int k = ks * 32 + quad * 8 + j;
      int c = k & 63, dt = k >> 6;
      float v = t1w[(o * 64 + c) * 3 + dt];
      if (o < 32 && dt == 2) v += aw[o * 64 + c];
      wglu[idx] = f2b(v);
    }
  } else if (mode == 1) {  // theta: M=32, K=96, KS=3 (padded to 512 chunks)
    for (int idx = tid; idx < 512 * 8; idx += 256) {
      int chunk = idx >> 3, j = idx & 7;
      int l15 = chunk & 15, quad = (chunk >> 4) & 3, g = chunk >> 6;
      float v = 0.f;
      if (g < 6) {
        int ks = g % 3, mi = g / 3;
        int o = mi * 16 + l15;
        int k = ks * 32 + quad * 8 + j;
        int i = k & 31, src = k >> 5;
        const float* p = th + (i * 32 + o) * 3;
        v = (src == 0) ? (p[0] - p[2]) : (src == 1 ? p[1] : 2.f * p[2]);
      }
      wth[idx] = f2b(v);
    }
  } else {  // t2: M=64, K=96, KS=3
    for (int idx = tid; idx < 768 * 8; idx += 256) {
      int chunk = idx >> 3, j = idx & 7;
      int l15 = chunk & 15, quad = (chunk >> 4) & 3, g = chunk >> 6;
      int ks = g % 3, mi = g / 3;
      int o = mi * 16 + l15;
      int k = ks * 32 + quad * 8 + j;
      int i = k & 31, dt = k >> 5;
      wt2[idx] = f2b(t2w[(o * 32 + i) * 3 + dt]);
    }
  }
}

// --------------------------- unified MFMA conv/mix kernel -------------------
// MODE 0 GLU:   out[i][n] = (D_sv + t1b+ab) * sigmoid(D_gate + t1b[32+])
// MODE 1 theta: out[o][n] = relu(D + sbias + X[o][n])
// MODE 2 t2:    out[o][n] = relu(D + t2b + (o<32 ? X[k=64+o][n] : 0))
template <int MODE>
__global__ __launch_bounds__(256, 2)
void k_mix(const u16* __restrict__ x0, const u16* __restrict__ y1,
           const u16* __restrict__ y2, const u16* __restrict__ wp,
           const float* __restrict__ b0, const float* __restrict__ b1,
           u16* __restrict__ out, int T_in, int T) {
  constexpr int M = (MODE == 1) ? 32 : 64;
  constexpr int K = (MODE == 0) ? 192 : 96;
  constexpr int KS = K / 32;
  constexpr int MT = M / 16;
  constexpr int WCH = ((MT * KS * 64) + 255) & ~255;  // frag chunks, pad x256
  constexpr int XCH = KS * 8 * 65;                    // 65-pad per (ks,nblk)
  __shared__ __align__(16) u16 lw[WCH * 8];
  __shared__ __align__(16) u16 lx[XCH * 8];

  const int tid = threadIdx.x;
  const int lane = tid & 63, wave = tid >> 6;
  const int quad = lane >> 4, l15 = lane & 15;
  const int n0 = blockIdx.x * 128;
  const int b = blockIdx.y / T, t = blockIdx.y % T;

  // stage packed weight frags: contiguous global -> contiguous LDS
#pragma unroll
  for (int p = 0; p < WCH / 256; ++p)
    gl_lds16(wp + (size_t)(p * 256 + wave * 64 + lane) * 8,
             &lw[(p * 256 + wave * 64) * 8]);

  // stage X^T tile (K x 128) transposed into frag-packed layout
  const bool guard = (MODE != 1) && (n0 + 128 > 2000);
  for (int p = 0; p < KS; ++p) {
    const int k4 = p * 8 + (tid >> 5);  // group of 4 consecutive k-rows
    const int nloc = (tid & 31) * 4;
    us4 rv[4];
#pragma unroll
    for (int i = 0; i < 4; ++i) {
      const int k = k4 * 4 + i;
      const u16* rp;
      if (MODE == 0) {
        rp = x0 + (size_t)((b * 64 + (k & 63)) * T_in + t + (k >> 6)) * 2000;
      } else if (MODE == 1) {
        const u16* base = (k < 32) ? x0 : ((k < 64) ? y1 : y2);
        rp = base + (size_t)((b * 32 + (k & 31)) * T_in + t) * 2048;
      } else {
        rp = x0 + (size_t)((b * 32 + (k & 31)) * T_in + t + (k >> 5)) * 2000;
      }
      rv[i] = guard ? load4_guard(rp + n0 + nloc, n0 + nloc)
                    : *(const us4*)(rp + n0 + nloc);
    }
    const int quadw = (k4 >> 1) & 3;
    const int j0 = (k4 & 1) * 4;
#pragma unroll
    for (int i = 0; i < 4; ++i) {
      const int nn = nloc + i;
      const int chunk = (p * 8 + (nn >> 4)) * 65 + quadw * 16 + (nn & 15);
      us4 wv;
      wv.v[0] = rv[0].v[i]; wv.v[1] = rv[1].v[i];
      wv.v[2] = rv[2].v[i]; wv.v[3] = rv[3].v[i];
      *(us4*)&lx[chunk * 8 + j0] = wv;  // ds_write_b64
    }
  }
  asm volatile("s_waitcnt vmcnt(0)" ::: "memory");
  __syncthreads();

  floatx4 acc[MT][2] = {};
#pragma unroll
  for (int ks = 0; ks < KS; ++ks) {
    short8 bfr[2], afr[MT];
#pragma unroll
    for (int nj = 0; nj < 2; ++nj)
      bfr[nj] = *(const short8*)&lx[(((ks * 8 + wave * 2 + nj) * 65) + lane) * 8];
#pragma unroll
    for (int mi = 0; mi < MT; ++mi)
      afr[mi] = *(const short8*)&lw[((mi * KS + ks) * 64 + lane) * 8];
#pragma unroll
    for (int mi = 0; mi < MT; ++mi)
#pragma unroll
      for (int nj = 0; nj < 2; ++nj)
        acc[mi][nj] = __builtin_amdgcn_mfma_f32_16x16x32_bf16(
            afr[mi], bfr[nj], acc[mi][nj], 0, 0, 0);
  }

  // epilogue (C/D layout: col=lane&15, row=quad*4+reg)
#pragma unroll
  for (int nj = 0; nj < 2; ++nj) {
    const int nblk = wave * 2 + nj;
    const int n = n0 + nblk * 16 + l15;
    if (MODE == 0) {
#pragma unroll
      for (int mi = 0; mi < 2; ++mi)
#pragma unroll
        for (int r = 0; r < 4; ++r) {
          const int i = mi * 16 + quad * 4 + r;
          const float sv = acc[mi][nj][r] + b0[i] + b1[i];
          const float gt = acc[mi + 2][nj][r] + b0[32 + i];
          const float val = sv / (1.f + __expf(-gt));
          out[(size_t)((b * 32 + i) * T + t) * 2048 + n] = f2b(val);
        }
    } else if (MODE == 1) {
#pragma unroll
      for (int mi = 0; mi < MT; ++mi)
#pragma unroll
        for (int r = 0; r < 4; ++r) {
          const int o = mi * 16 + quad * 4 + r;
          const int rc = nblk * 65 + ((o >> 3) & 3) * 16 + l15;  // resid X[o][n]
          float v = acc[mi][nj][r] + b0[o] + b2f(lx[rc * 8 + (o & 7)]);
          if (n < 2000)
            out[(size_t)((b * 32 + o) * T + t) * 2000 + n] = f2b(fmaxf(v, 0.f));
        }
    } else {
#pragma unroll
      for (int mi = 0; mi < MT; ++mi)
#pragma unroll
        for (int r = 0; r < 4; ++r) {
          const int o = mi * 16 + quad * 4 + r;
          float v = acc[mi][nj][r] + b0[o];
          if (o < 32) {  // channel-pad residual = X row k=64+o (dt=2)
            const int rc = (16 + nblk) * 65 + ((o >> 3) & 3) * 16 + l15;
            v += b2f(lx[rc * 8 + (o & 7)]);
          }
          if (n < 2000)
            out[(size_t)((b * 64 + o) * T + t) * 2000 + n] = f2b(fmaxf(v, 0.f));
        }
    }
  }
}

// --------------------------- bf16 MFMA GEMM (C = A * Bt^T) ------------------
__global__ __launch_bounds__(256, 2)
void k_gemm(const u16* __restrict__ A, const u16* __restrict__ Bt,
            u16* __restrict__ C) {
  constexpr int K = 2048;
  __shared__ u16 As[128 * 32];
  __shared__ u16 Bs[128 * 32];
  const int tid = threadIdx.x;
  const int lane = tid & 63, wave = tid >> 6;
  const int m0 = blockIdx.y * 128, n0 = blockIdx.x * 128;
  const int wy = wave >> 1, wx = wave & 1;
  const int quad = lane >> 4, l15 = lane & 15;

  const int c0 = wave * 128 + lane;
  const int c1 = c0 + 64;
  const u16* Ag0 = A + (size_t)(m0 + (c0 >> 2)) * K + (c0 & 3) * 8;
  const u16* Ag1 = A + (size_t)(m0 + (c1 >> 2)) * K + (c1 & 3) * 8;
  const u16* Bg0 = Bt + (size_t)(n0 + (c0 >> 2)) * K + (c0 & 3) * 8;
  const u16* Bg1 = Bt + (size_t)(n0 + (c1 >> 2)) * K + (c1 & 3) * 8;
  u16* lA0 = &As[(wave * 2 + 0) * 512];
  u16* lA1 = &As[(wave * 2 + 1) * 512];
  u16* lB0 = &Bs[(wave * 2 + 0) * 512];
  u16* lB1 = &Bs[(wave * 2 + 1) * 512];

  floatx4 acc[4][4] = {};

  for (int k0 = 0; k0 < K; k0 += 32) {
    gl_lds16(Ag0 + k0, lA0);
    gl_lds16(Ag1 + k0, lA1);
    gl_lds16(Bg0 + k0, lB0);
    gl_lds16(Bg1 + k0, lB1);
    asm volatile("s_waitcnt vmcnt(0)" ::: "memory");
    __syncthreads();

    short8 af[4], bf[4];
#pragma unroll
    for (int mi = 0; mi < 4; ++mi)
      af[mi] = *(const short8*)&As[(wy * 64 + mi * 16 + l15) * 32 + quad * 8];
#pragma unroll
    for (int ni = 0; ni < 4; ++ni)
      bf[ni] = *(const short8*)&Bs[(wx * 64 + ni * 16 + l15) * 32 + quad * 8];
#pragma unroll
    for (int mi = 0; mi < 4; ++mi)
#pragma unroll
      for (int ni = 0; ni < 4; ++ni)
        acc[mi][ni] = __builtin_amdgcn_mfma_f32_16x16x32_bf16(
            af[mi], bf[ni], acc[mi][ni], 0, 0, 0);
    __syncthreads();
  }

#pragma unroll
  for (int mi = 0; mi < 4; ++mi) {
#pragma unroll
    for (int ni = 0; ni < 4; ++ni) {
      const int row = m0 + wy * 64 + mi * 16 + quad * 4;
      const int col = n0 + wx * 64 + ni * 16 + l15;
#pragma unroll
      for (int r = 0; r < 4; ++r)
        C[(size_t)(row + r) * K + col] = f2b(acc[mi][ni][r]);
    }
  }
}

// --------------------------- LayerNorm --------------------------------------

__global__ void k_lnpart(const u16* __restrict__ h, float* __restrict__ part, int T) {
  const int bt = blockIdx.x, cg = blockIdx.y;
  const int b = bt / T, t = bt % T;
  const int tid = threadIdx.x;
  float s = 0.f, ss = 0.f;
  for (int c = cg * 8; c < cg * 8 + 8; ++c) {
    const u16* row = h + (size_t)((b * 64 + c) * T + t) * 2000;
    for (int n = tid * 4; n < 2000; n += 1024) {
      const us4 hv = *(const us4*)(row + n);
#pragma unroll
      for (int i = 0; i < 4; ++i) {
        const float v = b2f(hv.v[i]);
        s += v; ss += v * v;
      }
    }
  }
  __shared__ float r1[256], r2[256];
  r1[tid] = s; r2[tid] = ss;
  __syncthreads();
  for (int st = 128; st > 0; st >>= 1) {
    if (tid < st) { r1[tid] += r1[tid + st]; r2[tid] += r2[tid + st]; }
    __syncthreads();
  }
  if (tid == 0) {
    part[(bt * 8 + cg) * 2 + 0] = r1[0];
    part[(bt * 8 + cg) * 2 + 1] = r2[0];
  }
}

__global__ void k_lnfin(const float* __restrict__ part, float* __restrict__ stats,
                        int BT) {
  const int i = blockIdx.x * 256 + threadIdx.x;
  if (i >= BT) return;
  float s = 0.f, ss = 0.f;
  for (int g = 0; g < 8; ++g) {
    s  += part[(i * 8 + g) * 2 + 0];
    ss += part[(i * 8 + g) * 2 + 1];
  }
  const float inv = 1.f / 128000.f;
  const float mu = s * inv;
  const float var = ss * inv - mu * mu;
  stats[i * 2] = mu;
  stats[i * 2 + 1] = rsqrtf(var + 1e-5f);
}

__global__ void k_lnapply(u16* __restrict__ h, const float* __restrict__ stats,
                          const float* __restrict__ gw, const float* __restrict__ gb,
                          float* __restrict__ outf, int T, int write_f32) {
  const int n = blockIdx.x * 256 + threadIdx.x;
  int by = blockIdx.y;
  const int t = by % T; by /= T;
  const int c = by & 63;
  const int b = by >> 6;
  if (n >= 2000) return;
  const int bt = b * T + t;
  const float mu = stats[bt * 2], rs = stats[bt * 2 + 1];
  const size_t idx = (size_t)((b * 64 + c) * T + t) * 2000 + n;
  const float v = (b2f(h[idx]) - mu) * rs * gw[n * 64 + c] + gb[n * 64 + c];
  if (write_f32) outf[idx] = v;
  else h[idx] = f2b(v);
}

// --------------------------- launch -----------------------------------------

extern "C" void kernel_launch(void* const* d_in, const int* in_sizes, int n_in,
                              void* d_out, int out_size, void* d_ws, size_t ws_size,
                              hipStream_t stream) {
  const float* x     = (const float*)d_in[0];
  const float* graph = (const float*)d_in[1];
  const float* in_w  = (const float*)d_in[2];
  const float* in_b  = (const float*)d_in[3];

  char* ws = (char*)d_ws;
  size_t off = 0;
  auto alloc = [&](size_t bytes) -> void* {
    void* p = ws + off;
    off += (bytes + 255) & ~(size_t)255;
    return p;
  };
  float* dd    = (float*)alloc(2048 * 4);
  float* stats = (float*)alloc(16 * 12 * 2 * 4);
  float* part  = (float*)alloc(16 * 8 * 8 * 2 * 4);
  u16* wpg  = (u16*)alloc((size_t)1536 * 8 * 2);
  u16* wpt  = (u16*)alloc((size_t)512 * 8 * 2);
  u16* wp2  = (u16*)alloc((size_t)768 * 8 * 2);
  u16* L    = (u16*)alloc((size_t)2048 * 2048 * 2);
  u16* h0   = (u16*)alloc((size_t)16 * 64 * 12 * 2000 * 2);
  u16* Xp   = (u16*)alloc((size_t)5120 * 2048 * 2);
  u16* Y1   = (u16*)alloc((size_t)5120 * 2048 * 2);
  u16* Y2   = (u16*)alloc((size_t)5120 * 2048 * 2);
  u16* sbuf = (u16*)alloc((size_t)16 * 32 * 10 * 2000 * 2);
  u16* h1   = (u16*)alloc((size_t)16 * 64 * 8 * 2000 * 2);
  u16* h2   = h0;  // reuse: h0 dead after block-1 GLU
  if (off > ws_size) return;

  k_deg<<<dim3(2000), dim3(256), 0, stream>>>(graph, dd);
  k_lap<<<dim3(8, 2048), dim3(256), 0, stream>>>(graph, dd, L);
  k_inconv<<<dim3(8, 192), dim3(256), 0, stream>>>(x, in_w, in_b, h0);

  for (int blk = 0; blk < 2; ++blk) {
    const int base = 4 + blk * 10;
    const float* t1w = (const float*)d_in[base + 0];
    const float* t1b = (const float*)d_in[base + 1];
    const float* aw  = (const float*)d_in[base + 2];
    const float* ab  = (const float*)d_in[base + 3];
    const float* th  = (const float*)d_in[base + 4];
    const float* sb  = (const float*)d_in[base + 5];
    const float* t2w = (const float*)d_in[base + 6];
    const float* t2b = (const float*)d_in[base + 7];
    const float* lng = (const float*)d_in[base + 8];
    const float* lnb = (const float*)d_in[base + 9];

    const int T_in = (blk == 0) ? 12 : 8;
    const int T_g  = T_in - 2;  // 10 / 6
    const int T_o  = T_g - 2;   // 8 / 4
    const u16* hin = (blk == 0) ? h0 : h1;
    u16* hout      = (blk == 0) ? h1 : h2;
    const int M = 16 * 32 * T_g;  // 5120 / 3072

    k_wpack<<<dim3(3), dim3(256), 0, stream>>>(t1w, aw, th, t2w, wpg, wpt, wp2);
    k_mix<0><<<dim3(16, 16 * T_g), dim3(256), 0, stream>>>(
        hin, nullptr, nullptr, wpg, t1b, ab, Xp, T_in, T_g);
    k_gemm<<<dim3(16, M / 128), dim3(256), 0, stream>>>(Xp, L, Y1);
    k_gemm<<<dim3(16, M / 128), dim3(256), 0, stream>>>(Y1, L, Y2);
    k_mix<1><<<dim3(16, 16 * T_g), dim3(256), 0, stream>>>(
        Xp, Y1, Y2, wpt, sb, nullptr, sbuf, T_g, T_g);
    k_mix<2><<<dim3(16, 16 * T_o), dim3(256), 0, stream>>>(
        sbuf, nullptr, nullptr, wp2, t2b, nullptr, hout, T_g, T_o);
    k_lnpart<<<dim3(16 * T_o, 8), dim3(256), 0, stream>>>(hout, part, T_o);
    k_lnfin<<<dim3(1), dim3(256), 0, stream>>>(part, stats, 16 * T_o);
    k_lnapply<<<dim3(8, 16 * 64 * T_o), dim3(256), 0, stream>>>(
        hout, stats, lng, lnb, (float*)d_out, T_o, blk);
  }
}

// Round 3
// 611.980 us; speedup vs baseline: 2.3757x; 1.2012x over previous
//
#include <hip/hip_runtime.h>

// ---------------------------------------------------------------------------
// STEncoder (STGCN-style) on MI355X.
// B=16, N=2000 (pad 2048), T=12, D_IN=3, C=64, CM=32, KS=KT=3.
// GLU/theta/t2 convs are small-M GEMMs -> unified MFMA kernel k_mix with
// frag-packed LDS staging. Chebyshev: T0=I, T2=2L^2-I -> 2 big GEMMs/block.
// R3: transposed LN gamma/beta (kill stride-256B gather), vectorized
//     elementwise kernels, GEMM wave-tile 64x128 (32 MFMA / 12 ds_read).
// ---------------------------------------------------------------------------

typedef unsigned short u16;
typedef __attribute__((ext_vector_type(8))) short short8;   // 8 x bf16 frag
typedef __attribute__((ext_vector_type(4))) float floatx4;  // MFMA acc

struct __attribute__((aligned(8))) us4 { u16 v[4]; };

#define AS1 __attribute__((address_space(1)))
#define AS3 __attribute__((address_space(3)))

__device__ __forceinline__ float b2f(u16 h) {
  union { unsigned int u; float f; } v;
  v.u = ((unsigned int)h) << 16;
  return v.f;
}
__device__ __forceinline__ u16 f2b(float f) {
  union { float f; unsigned int u; } v;
  v.f = f;
  unsigned int r = (v.u + 0x7fffu + ((v.u >> 16) & 1u)) >> 16;
  return (u16)r;
}
__device__ __forceinline__ void gl_lds16(const u16* g, u16* l) {
  __builtin_amdgcn_global_load_lds((const AS1 unsigned int*)g,
                                   (AS3 unsigned int*)l, 16, 0, 0);
}
__device__ __forceinline__ us4 load4_guard(const u16* gp, int n) {
  if (n + 3 < 2000) return *(const us4*)gp;
  us4 r;
#pragma unroll
  for (int i = 0; i < 4; ++i) r.v[i] = (n + i < 2000) ? gp[i] : (u16)0;
  return r;
}

// --------------------------- graph preprocessing ---------------------------

__global__ void k_deg(const float* __restrict__ graph, float* __restrict__ d) {
  const int n = blockIdx.x;
  const int tid = threadIdx.x;
  float s = 0.f;
  const float* row = graph + (size_t)n * 2000;
  for (int m4 = tid; m4 < 500; m4 += 256) {
    const float4 g = *(const float4*)(row + m4 * 4);
    s += (g.x + g.y) + (g.z + g.w);
  }
  __shared__ float red[256];
  red[tid] = s;
  __syncthreads();
  for (int st = 128; st > 0; st >>= 1) {
    if (tid < st) red[tid] += red[tid + st];
    __syncthreads();
  }
  if (tid == 0) d[n] = rsqrtf(fmaxf(red[0] + 1.f, 1e-6f));
}

__global__ void k_lap(const float* __restrict__ graph, const float* __restrict__ d,
                      u16* __restrict__ L) {
  const int m = blockIdx.x * 1024 + threadIdx.x * 4;
  const int n = blockIdx.y;
  us4 r = {{0, 0, 0, 0}};
  if (n < 2000 && m < 2000) {  // 2000%4==0: chunks never straddle the edge
    const float4 g4 = *(const float4*)(graph + (size_t)n * 2000 + m);
    const float4 d4 = *(const float4*)(d + m);
    const float dn = d[n];
    const float gv[4] = {g4.x, g4.y, g4.z, g4.w};
    const float dv[4] = {d4.x, d4.y, d4.z, d4.w};
#pragma unroll
    for (int i = 0; i < 4; ++i) {
      const float delta = (n == m + i) ? 1.f : 0.f;
      r.v[i] = f2b(delta - dn * (gv[i] + delta) * dv[i]);
    }
  }
  *(us4*)(L + (size_t)n * 2048 + m) = r;
}

// --------------------------- input 1x1 conv (K=3) ---------------------------

__global__ void k_inconv(const float* __restrict__ x, const float* __restrict__ w,
                         const float* __restrict__ bias, u16* __restrict__ h0) {
  const int n = blockIdx.x * 1024 + threadIdx.x * 4;
  if (n >= 2000) return;
  const int b = blockIdx.y / 12, t = blockIdx.y % 12;
  const float4 x0 = *(const float4*)(x + ((size_t)(b * 3 + 0) * 12 + t) * 2000 + n);
  const float4 x1 = *(const float4*)(x + ((size_t)(b * 3 + 1) * 12 + t) * 2000 + n);
  const float4 x2 = *(const float4*)(x + ((size_t)(b * 3 + 2) * 12 + t) * 2000 + n);
  for (int o = 0; o < 64; ++o) {
    const float w0 = w[o], w1 = w[64 + o], w2 = w[128 + o], bb = bias[o];
    us4 r;
    r.v[0] = f2b(x0.x * w0 + x1.x * w1 + x2.x * w2 + bb);
    r.v[1] = f2b(x0.y * w0 + x1.y * w1 + x2.y * w2 + bb);
    r.v[2] = f2b(x0.z * w0 + x1.z * w1 + x2.z * w2 + bb);
    r.v[3] = f2b(x0.w * w0 + x1.w * w1 + x2.w * w2 + bb);
    *(us4*)(h0 + ((size_t)(b * 64 + o) * 12 + t) * 2000 + n) = r;
  }
}

// --------------------------- weight fragment packing ------------------------
__global__ void k_wpack(const float* __restrict__ t1w, const float* __restrict__ aw,
                        const float* __restrict__ th, const float* __restrict__ t2w,
                        u16* __restrict__ wglu, u16* __restrict__ wth,
                        u16* __restrict__ wt2) {
  const int mode = blockIdx.x;
  const int tid = threadIdx.x;
  if (mode == 0) {  // GLU: M=64, K=192, KS=6
    for (int idx = tid; idx < 1536 * 8; idx += 256) {
      int chunk = idx >> 3, j = idx & 7;
      int l15 = chunk & 15, quad = (chunk >> 4) & 3, g = chunk >> 6;
      int ks = g % 6, mi = g / 6;
      int o = mi * 16 + l15;
      int k = ks * 32 + quad * 8 + j;
      int c = k & 63, dt = k >> 6;
      float v = t1w[(o * 64 + c) * 3 + dt];
      if (o < 32 && dt == 2) v += aw[o * 64 + c];
      wglu[idx] = f2b(v);
    }
  } else if (mode == 1) {  // theta: M=32, K=96, KS=3 (padded to 512 chunks)
    for (int idx = tid; idx < 512 * 8; idx += 256) {
      int chunk = idx >> 3, j = idx & 7;
      int l15 = chunk & 15, quad = (chunk >> 4) & 3, g = chunk >> 6;
      float v = 0.f;
      if (g < 6) {
        int ks = g % 3, mi = g / 3;
        int o = mi * 16 + l15;
        int k = ks * 32 + quad * 8 + j;
        int i = k & 31, src = k >> 5;
        const float* p = th + (i * 32 + o) * 3;
        v = (src == 0) ? (p[0] - p[2]) : (src == 1 ? p[1] : 2.f * p[2]);
      }
      wth[idx] = f2b(v);
    }
  } else {  // t2: M=64, K=96, KS=3
    for (int idx = tid; idx < 768 * 8; idx += 256) {
      int chunk = idx >> 3, j = idx & 7;
      int l15 = chunk & 15, quad = (chunk >> 4) & 3, g = chunk >> 6;
      int ks = g % 3, mi = g / 3;
      int o = mi * 16 + l15;
      int k = ks * 32 + quad * 8 + j;
      int i = k & 31, dt = k >> 5;
      wt2[idx] = f2b(t2w[(o * 32 + i) * 3 + dt]);
    }
  }
}

// --------------------------- unified MFMA conv/mix kernel -------------------
template <int MODE>
__global__ __launch_bounds__(256, 2)
void k_mix(const u16* __restrict__ x0, const u16* __restrict__ y1,
           const u16* __restrict__ y2, const u16* __restrict__ wp,
           const float* __restrict__ b0, const float* __restrict__ b1,
           u16* __restrict__ out, int T_in, int T) {
  constexpr int M = (MODE == 1) ? 32 : 64;
  constexpr int K = (MODE == 0) ? 192 : 96;
  constexpr int KS = K / 32;
  constexpr int MT = M / 16;
  constexpr int WCH = ((MT * KS * 64) + 255) & ~255;
  constexpr int XCH = KS * 8 * 65;
  __shared__ __align__(16) u16 lw[WCH * 8];
  __shared__ __align__(16) u16 lx[XCH * 8];

  const int tid = threadIdx.x;
  const int lane = tid & 63, wave = tid >> 6;
  const int quad = lane >> 4, l15 = lane & 15;
  const int n0 = blockIdx.x * 128;
  const int b = blockIdx.y / T, t = blockIdx.y % T;

#pragma unroll
  for (int p = 0; p < WCH / 256; ++p)
    gl_lds16(wp + (size_t)(p * 256 + wave * 64 + lane) * 8,
             &lw[(p * 256 + wave * 64) * 8]);

  const bool guard = (MODE != 1) && (n0 + 128 > 2000);
  for (int p = 0; p < KS; ++p) {
    const int k4 = p * 8 + (tid >> 5);
    const int nloc = (tid & 31) * 4;
    us4 rv[4];
#pragma unroll
    for (int i = 0; i < 4; ++i) {
      const int k = k4 * 4 + i;
      const u16* rp;
      if (MODE == 0) {
        rp = x0 + (size_t)((b * 64 + (k & 63)) * T_in + t + (k >> 6)) * 2000;
      } else if (MODE == 1) {
        const u16* base = (k < 32) ? x0 : ((k < 64) ? y1 : y2);
        rp = base + (size_t)((b * 32 + (k & 31)) * T_in + t) * 2048;
      } else {
        rp = x0 + (size_t)((b * 32 + (k & 31)) * T_in + t + (k >> 5)) * 2000;
      }
      rv[i] = guard ? load4_guard(rp + n0 + nloc, n0 + nloc)
                    : *(const us4*)(rp + n0 + nloc);
    }
    const int quadw = (k4 >> 1) & 3;
    const int j0 = (k4 & 1) * 4;
#pragma unroll
    for (int i = 0; i < 4; ++i) {
      const int nn = nloc + i;
      const int chunk = (p * 8 + (nn >> 4)) * 65 + quadw * 16 + (nn & 15);
      us4 wv;
      wv.v[0] = rv[0].v[i]; wv.v[1] = rv[1].v[i];
      wv.v[2] = rv[2].v[i]; wv.v[3] = rv[3].v[i];
      *(us4*)&lx[chunk * 8 + j0] = wv;
    }
  }
  asm volatile("s_waitcnt vmcnt(0)" ::: "memory");
  __syncthreads();

  floatx4 acc[MT][2] = {};
#pragma unroll
  for (int ks = 0; ks < KS; ++ks) {
    short8 bfr[2], afr[MT];
#pragma unroll
    for (int nj = 0; nj < 2; ++nj)
      bfr[nj] = *(const short8*)&lx[(((ks * 8 + wave * 2 + nj) * 65) + lane) * 8];
#pragma unroll
    for (int mi = 0; mi < MT; ++mi)
      afr[mi] = *(const short8*)&lw[((mi * KS + ks) * 64 + lane) * 8];
#pragma unroll
    for (int mi = 0; mi < MT; ++mi)
#pragma unroll
      for (int nj = 0; nj < 2; ++nj)
        acc[mi][nj] = __builtin_amdgcn_mfma_f32_16x16x32_bf16(
            afr[mi], bfr[nj], acc[mi][nj], 0, 0, 0);
  }

#pragma unroll
  for (int nj = 0; nj < 2; ++nj) {
    const int nblk = wave * 2 + nj;
    const int n = n0 + nblk * 16 + l15;
    if (MODE == 0) {
#pragma unroll
      for (int mi = 0; mi < 2; ++mi)
#pragma unroll
        for (int r = 0; r < 4; ++r) {
          const int i = mi * 16 + quad * 4 + r;
          const float sv = acc[mi][nj][r] + b0[i] + b1[i];
          const float gt = acc[mi + 2][nj][r] + b0[32 + i];
          const float val = sv / (1.f + __expf(-gt));
          out[(size_t)((b * 32 + i) * T + t) * 2048 + n] = f2b(val);
        }
    } else if (MODE == 1) {
#pragma unroll
      for (int mi = 0; mi < MT; ++mi)
#pragma unroll
        for (int r = 0; r < 4; ++r) {
          const int o = mi * 16 + quad * 4 + r;
          const int rc = nblk * 65 + ((o >> 3) & 3) * 16 + l15;
          float v = acc[mi][nj][r] + b0[o] + b2f(lx[rc * 8 + (o & 7)]);
          if (n < 2000)
            out[(size_t)((b * 32 + o) * T + t) * 2000 + n] = f2b(fmaxf(v, 0.f));
        }
    } else {
#pragma unroll
      for (int mi = 0; mi < MT; ++mi)
#pragma unroll
        for (int r = 0; r < 4; ++r) {
          const int o = mi * 16 + quad * 4 + r;
          float v = acc[mi][nj][r] + b0[o];
          if (o < 32) {
            const int rc = (16 + nblk) * 65 + ((o >> 3) & 3) * 16 + l15;
            v += b2f(lx[rc * 8 + (o & 7)]);
          }
          if (n < 2000)
            out[(size_t)((b * 64 + o) * T + t) * 2000 + n] = f2b(fmaxf(v, 0.f));
        }
    }
  }
}

// --------------------------- bf16 MFMA GEMM (C = A * Bt^T) ------------------
// 128-thread blocks, block tile 128x128, wave-tile 64m x 128n:
// 32 MFMA per 12 ds_read_b128 -> matrix pipe is the binding resource.
// Wave 0 stages the A tile, wave 1 stages the B tile (8 gl_lds16 each).
__global__ __launch_bounds__(128, 2)
void k_gemm(const u16* __restrict__ A, const u16* __restrict__ Bt,
            u16* __restrict__ C) {
  constexpr int K = 2048;
  __shared__ u16 As[128 * 32];
  __shared__ u16 Bs[128 * 32];
  const int tid = threadIdx.x;
  const int lane = tid & 63, wave = tid >> 6;
  const int m0 = blockIdx.y * 128, n0 = blockIdx.x * 128;
  const int quad = lane >> 4, l15 = lane & 15;

  const u16* gsrc = ((wave == 0)
                         ? (A + (size_t)(m0 + (lane >> 2)) * K)
                         : (Bt + (size_t)(n0 + (lane >> 2)) * K)) +
                    (lane & 3) * 8;
  u16* lbase = (wave == 0) ? As : Bs;

  floatx4 acc[4][8] = {};

  for (int k0 = 0; k0 < K; k0 += 32) {
#pragma unroll
    for (int p = 0; p < 8; ++p)
      gl_lds16(gsrc + k0 + (size_t)p * 16 * K, lbase + p * 512);
    asm volatile("s_waitcnt vmcnt(0)" ::: "memory");
    __syncthreads();

    short8 af[4], bf[8];
#pragma unroll
    for (int mi = 0; mi < 4; ++mi)
      af[mi] = *(const short8*)&As[(wave * 64 + mi * 16 + l15) * 32 + quad * 8];
#pragma unroll
    for (int ni = 0; ni < 8; ++ni)
      bf[ni] = *(const short8*)&Bs[(ni * 16 + l15) * 32 + quad * 8];
#pragma unroll
    for (int mi = 0; mi < 4; ++mi)
#pragma unroll
      for (int ni = 0; ni < 8; ++ni)
        acc[mi][ni] = __builtin_amdgcn_mfma_f32_16x16x32_bf16(
            af[mi], bf[ni], acc[mi][ni], 0, 0, 0);
    __syncthreads();
  }

#pragma unroll
  for (int mi = 0; mi < 4; ++mi) {
#pragma unroll
    for (int ni = 0; ni < 8; ++ni) {
      const int row = m0 + wave * 64 + mi * 16 + quad * 4;
      const int col = n0 + ni * 16 + l15;
#pragma unroll
      for (int r = 0; r < 4; ++r)
        C[(size_t)(row + r) * K + col] = f2b(acc[mi][ni][r]);
    }
  }
}

// --------------------------- LayerNorm --------------------------------------

__global__ void k_lnpart(const u16* __restrict__ h, float* __restrict__ part, int T) {
  const int bt = blockIdx.x, cg = blockIdx.y;
  const int b = bt / T, t = bt % T;
  const int tid = threadIdx.x;
  float s = 0.f, ss = 0.f;
  for (int c = cg * 8; c < cg * 8 + 8; ++c) {
    const u16* row = h + (size_t)((b * 64 + c) * T + t) * 2000;
    for (int n = tid * 4; n < 2000; n += 1024) {
      const us4 hv = *(const us4*)(row + n);
#pragma unroll
      for (int i = 0; i < 4; ++i) {
        const float v = b2f(hv.v[i]);
        s += v; ss += v * v;
      }
    }
  }
  __shared__ float r1[256], r2[256];
  r1[tid] = s; r2[tid] = ss;
  __syncthreads();
  for (int st = 128; st > 0; st >>= 1) {
    if (tid < st) { r1[tid] += r1[tid + st]; r2[tid] += r2[tid + st]; }
    __syncthreads();
  }
  if (tid == 0) {
    part[(bt * 8 + cg) * 2 + 0] = r1[0];
    part[(bt * 8 + cg) * 2 + 1] = r2[0];
  }
}

__global__ void k_lnfin(const float* __restrict__ part, float* __restrict__ stats,
                        int BT) {
  const int i = blockIdx.x * 256 + threadIdx.x;
  if (i >= BT) return;
  float s = 0.f, ss = 0.f;
  for (int g = 0; g < 8; ++g) {
    s  += part[(i * 8 + g) * 2 + 0];
    ss += part[(i * 8 + g) * 2 + 1];
  }
  const float inv = 1.f / 128000.f;
  const float mu = s * inv;
  const float var = ss * inv - mu * mu;
  stats[i * 2] = mu;
  stats[i * 2 + 1] = rsqrtf(var + 1e-5f);
}

// transpose gamma/beta [2000,64] -> [64,2048] (pad zeros)
__global__ void k_lngbT(const float* __restrict__ gw, const float* __restrict__ gb,
                        float* __restrict__ gwT, float* __restrict__ gbT) {
  const int n = blockIdx.x * 256 + threadIdx.x;
  const int c = blockIdx.y;
  float vw = 0.f, vb = 0.f;
  if (n < 2000) {
    vw = gw[(size_t)n * 64 + c];
    vb = gb[(size_t)n * 64 + c];
  }
  gwT[(size_t)c * 2048 + n] = vw;
  gbT[(size_t)c * 2048 + n] = vb;
}

__global__ void k_lnapply(u16* __restrict__ h, const float* __restrict__ stats,
                          const float* __restrict__ gwT, const float* __restrict__ gbT,
                          float* __restrict__ outf, int T, int write_f32) {
  const int n = blockIdx.x * 1024 + threadIdx.x * 4;
  if (n >= 2000) return;  // 2000%4==0: full chunks only
  int by = blockIdx.y;
  const int t = by % T; by /= T;
  const int c = by & 63;
  const int b = by >> 6;
  const int bt = b * T + t;
  const float mu = stats[bt * 2], rs = stats[bt * 2 + 1];
  const size_t row = (size_t)((b * 64 + c) * T + t) * 2000 + n;
  const us4 hv = *(const us4*)(h + row);
  const float4 w4 = *(const float4*)(gwT + (size_t)c * 2048 + n);
  const float4 b4 = *(const float4*)(gbT + (size_t)c * 2048 + n);
  const float o0 = (b2f(hv.v[0]) - mu) * rs * w4.x + b4.x;
  const float o1 = (b2f(hv.v[1]) - mu) * rs * w4.y + b4.y;
  const float o2 = (b2f(hv.v[2]) - mu) * rs * w4.z + b4.z;
  const float o3 = (b2f(hv.v[3]) - mu) * rs * w4.w + b4.w;
  if (write_f32) {
    *(float4*)(outf + row) = make_float4(o0, o1, o2, o3);
  } else {
    us4 r;
    r.v[0] = f2b(o0); r.v[1] = f2b(o1); r.v[2] = f2b(o2); r.v[3] = f2b(o3);
    *(us4*)(h + row) = r;
  }
}

// --------------------------- launch -----------------------------------------

extern "C" void kernel_launch(void* const* d_in, const int* in_sizes, int n_in,
                              void* d_out, int out_size, void* d_ws, size_t ws_size,
                              hipStream_t stream) {
  const float* x     = (const float*)d_in[0];
  const float* graph = (const float*)d_in[1];
  const float* in_w  = (const float*)d_in[2];
  const float* in_b  = (const float*)d_in[3];

  char* ws = (char*)d_ws;
  size_t off = 0;
  auto alloc = [&](size_t bytes) -> void* {
    void* p = ws + off;
    off += (bytes + 255) & ~(size_t)255;
    return p;
  };
  float* dd    = (float*)alloc(2048 * 4);
  float* stats = (float*)alloc(16 * 12 * 2 * 4);
  float* part  = (float*)alloc(16 * 8 * 8 * 2 * 4);
  float* gwT   = (float*)alloc((size_t)64 * 2048 * 4);
  float* gbT   = (float*)alloc((size_t)64 * 2048 * 4);
  u16* wpg  = (u16*)alloc((size_t)1536 * 8 * 2);
  u16* wpt  = (u16*)alloc((size_t)512 * 8 * 2);
  u16* wp2  = (u16*)alloc((size_t)768 * 8 * 2);
  u16* L    = (u16*)alloc((size_t)2048 * 2048 * 2);
  u16* h0   = (u16*)alloc((size_t)16 * 64 * 12 * 2000 * 2);
  u16* Xp   = (u16*)alloc((size_t)5120 * 2048 * 2);
  u16* Y1   = (u16*)alloc((size_t)5120 * 2048 * 2);
  u16* Y2   = (u16*)alloc((size_t)5120 * 2048 * 2);
  u16* sbuf = (u16*)alloc((size_t)16 * 32 * 10 * 2000 * 2);
  u16* h1   = (u16*)alloc((size_t)16 * 64 * 8 * 2000 * 2);
  u16* h2   = h0;  // reuse: h0 dead after block-1 GLU
  if (off > ws_size) return;

  k_deg<<<dim3(2000), dim3(256), 0, stream>>>(graph, dd);
  k_lap<<<dim3(2, 2048), dim3(256), 0, stream>>>(graph, dd, L);
  k_inconv<<<dim3(2, 192), dim3(256), 0, stream>>>(x, in_w, in_b, h0);

  for (int blk = 0; blk < 2; ++blk) {
    const int base = 4 + blk * 10;
    const float* t1w = (const float*)d_in[base + 0];
    const float* t1b = (const float*)d_in[base + 1];
    const float* aw  = (const float*)d_in[base + 2];
    const float* ab  = (const float*)d_in[base + 3];
    const float* th  = (const float*)d_in[base + 4];
    const float* sb  = (const float*)d_in[base + 5];
    const float* t2w = (const float*)d_in[base + 6];
    const float* t2b = (const float*)d_in[base + 7];
    const float* lng = (const float*)d_in[base + 8];
    const float* lnb = (const float*)d_in[base + 9];

    const int T_in = (blk == 0) ? 12 : 8;
    const int T_g  = T_in - 2;  // 10 / 6
    const int T_o  = T_g - 2;   // 8 / 4
    const u16* hin = (blk == 0) ? h0 : h1;
    u16* hout      = (blk == 0) ? h1 : h2;
    const int M = 16 * 32 * T_g;  // 5120 / 3072

    k_wpack<<<dim3(3), dim3(256), 0, stream>>>(t1w, aw, th, t2w, wpg, wpt, wp2);
    k_lngbT<<<dim3(8, 64), dim3(256), 0, stream>>>(lng, lnb, gwT, gbT);
    k_mix<0><<<dim3(16, 16 * T_g), dim3(256), 0, stream>>>(
        hin, nullptr, nullptr, wpg, t1b, ab, Xp, T_in, T_g);
    k_gemm<<<dim3(16, M / 128), dim3(128), 0, stream>>>(Xp, L, Y1);
    k_gemm<<<dim3(16, M / 128), dim3(128), 0, stream>>>(Y1, L, Y2);
    k_mix<1><<<dim3(16, 16 * T_g), dim3(256), 0, stream>>>(
        Xp, Y1, Y2, wpt, sb, nullptr, sbuf, T_g, T_g);
    k_mix<2><<<dim3(16, 16 * T_o), dim3(256), 0, stream>>>(
        sbuf, nullptr, nullptr, wp2, t2b, nullptr, hout, T_g, T_o);
    k_lnpart<<<dim3(16 * T_o, 8), dim3(256), 0, stream>>>(hout, part, T_o);
    k_lnfin<<<dim3(1), dim3(256), 0, stream>>>(part, stats, 16 * T_o);
    k_lnapply<<<dim3(2, 16 * 64 * T_o), dim3(256), 0, stream>>>(
        hout, stats, gwT, gbT, (float*)d_out, T_o, blk);
  }
}

// Round 4
// 576.889 us; speedup vs baseline: 2.5202x; 1.0608x over previous
//
#include <hip/hip_runtime.h>

// ---------------------------------------------------------------------------
// STEncoder (STGCN-style) on MI355X.
// B=16, N=2000 (pad 2048), T=12, D_IN=3, C=64, CM=32, KS=KT=3.
// GLU/theta/t2 convs are small-M GEMMs -> unified MFMA kernel k_mix with
// frag-packed LDS staging. Chebyshev: T0=I, T2=2L^2-I -> 2 big GEMMs/block.
// R4: k_gemm gets (a) sigma-swizzled LDS layout (2-way = conflict-free
//     ds_read_b128) and (b) explicit double-buffer K-loop with raw s_barrier
//     + per-wave vmcnt, overlapping tile k+1 DMA with tile k compute.
// ---------------------------------------------------------------------------

typedef unsigned short u16;
typedef __attribute__((ext_vector_type(8))) short short8;   // 8 x bf16 frag
typedef __attribute__((ext_vector_type(4))) float floatx4;  // MFMA acc

struct __attribute__((aligned(8))) us4 { u16 v[4]; };

#define AS1 __attribute__((address_space(1)))
#define AS3 __attribute__((address_space(3)))

__device__ __forceinline__ float b2f(u16 h) {
  union { unsigned int u; float f; } v;
  v.u = ((unsigned int)h) << 16;
  return v.f;
}
__device__ __forceinline__ u16 f2b(float f) {
  union { float f; unsigned int u; } v;
  v.f = f;
  unsigned int r = (v.u + 0x7fffu + ((v.u >> 16) & 1u)) >> 16;
  return (u16)r;
}
__device__ __forceinline__ void gl_lds16(const u16* g, u16* l) {
  __builtin_amdgcn_global_load_lds((const AS1 unsigned int*)g,
                                   (AS3 unsigned int*)l, 16, 0, 0);
}
__device__ __forceinline__ us4 load4_guard(const u16* gp, int n) {
  if (n + 3 < 2000) return *(const us4*)gp;
  us4 r;
#pragma unroll
  for (int i = 0; i < 4; ++i) r.v[i] = (n + i < 2000) ? gp[i] : (u16)0;
  return r;
}

// --------------------------- graph preprocessing ---------------------------

__global__ void k_deg(const float* __restrict__ graph, float* __restrict__ d) {
  const int n = blockIdx.x;
  const int tid = threadIdx.x;
  float s = 0.f;
  const float* row = graph + (size_t)n * 2000;
  for (int m4 = tid; m4 < 500; m4 += 256) {
    const float4 g = *(const float4*)(row + m4 * 4);
    s += (g.x + g.y) + (g.z + g.w);
  }
  __shared__ float red[256];
  red[tid] = s;
  __syncthreads();
  for (int st = 128; st > 0; st >>= 1) {
    if (tid < st) red[tid] += red[tid + st];
    __syncthreads();
  }
  if (tid == 0) d[n] = rsqrtf(fmaxf(red[0] + 1.f, 1e-6f));
}

__global__ void k_lap(const float* __restrict__ graph, const float* __restrict__ d,
                      u16* __restrict__ L) {
  const int m = blockIdx.x * 1024 + threadIdx.x * 4;
  const int n = blockIdx.y;
  us4 r = {{0, 0, 0, 0}};
  if (n < 2000 && m < 2000) {  // 2000%4==0: chunks never straddle the edge
    const float4 g4 = *(const float4*)(graph + (size_t)n * 2000 + m);
    const float4 d4 = *(const float4*)(d + m);
    const float dn = d[n];
    const float gv[4] = {g4.x, g4.y, g4.z, g4.w};
    const float dv[4] = {d4.x, d4.y, d4.z, d4.w};
#pragma unroll
    for (int i = 0; i < 4; ++i) {
      const float delta = (n == m + i) ? 1.f : 0.f;
      r.v[i] = f2b(delta - dn * (gv[i] + delta) * dv[i]);
    }
  }
  *(us4*)(L + (size_t)n * 2048 + m) = r;
}

// --------------------------- input 1x1 conv (K=3) ---------------------------

__global__ void k_inconv(const float* __restrict__ x, const float* __restrict__ w,
                         const float* __restrict__ bias, u16* __restrict__ h0) {
  const int n = blockIdx.x * 1024 + threadIdx.x * 4;
  if (n >= 2000) return;
  const int b = blockIdx.y / 12, t = blockIdx.y % 12;
  const float4 x0 = *(const float4*)(x + ((size_t)(b * 3 + 0) * 12 + t) * 2000 + n);
  const float4 x1 = *(const float4*)(x + ((size_t)(b * 3 + 1) * 12 + t) * 2000 + n);
  const float4 x2 = *(const float4*)(x + ((size_t)(b * 3 + 2) * 12 + t) * 2000 + n);
  for (int o = 0; o < 64; ++o) {
    const float w0 = w[o], w1 = w[64 + o], w2 = w[128 + o], bb = bias[o];
    us4 r;
    r.v[0] = f2b(x0.x * w0 + x1.x * w1 + x2.x * w2 + bb);
    r.v[1] = f2b(x0.y * w0 + x1.y * w1 + x2.y * w2 + bb);
    r.v[2] = f2b(x0.z * w0 + x1.z * w1 + x2.z * w2 + bb);
    r.v[3] = f2b(x0.w * w0 + x1.w * w1 + x2.w * w2 + bb);
    *(us4*)(h0 + ((size_t)(b * 64 + o) * 12 + t) * 2000 + n) = r;
  }
}

// --------------------------- weight fragment packing ------------------------
__global__ void k_wpack(const float* __restrict__ t1w, const float* __restrict__ aw,
                        const float* __restrict__ th, const float* __restrict__ t2w,
                        u16* __restrict__ wglu, u16* __restrict__ wth,
                        u16* __restrict__ wt2) {
  const int mode = blockIdx.x;
  const int tid = threadIdx.x;
  if (mode == 0) {  // GLU: M=64, K=192, KS=6
    for (int idx = tid; idx < 1536 * 8; idx += 256) {
      int chunk = idx >> 3, j = idx & 7;
      int l15 = chunk & 15, quad = (chunk >> 4) & 3, g = chunk >> 6;
      int ks = g % 6, mi = g / 6;
      int o = mi * 16 + l15;
      int k = ks * 32 + quad * 8 + j;
      int c = k & 63, dt = k >> 6;
      float v = t1w[(o * 64 + c) * 3 + dt];
      if (o < 32 && dt == 2) v += aw[o * 64 + c];
      wglu[idx] = f2b(v);
    }
  } else if (mode == 1) {  // theta: M=32, K=96, KS=3 (padded to 512 chunks)
    for (int idx = tid; idx < 512 * 8; idx += 256) {
      int chunk = idx >> 3, j = idx & 7;
      int l15 = chunk & 15, quad = (chunk >> 4) & 3, g = chunk >> 6;
      float v = 0.f;
      if (g < 6) {
        int ks = g % 3, mi = g / 3;
        int o = mi * 16 + l15;
        int k = ks * 32 + quad * 8 + j;
        int i = k & 31, src = k >> 5;
        const float* p = th + (i * 32 + o) * 3;
        v = (src == 0) ? (p[0] - p[2]) : (src == 1 ? p[1] : 2.f * p[2]);
      }
      wth[idx] = f2b(v);
    }
  } else {  // t2: M=64, K=96, KS=3
    for (int idx = tid; idx < 768 * 8; idx += 256) {
      int chunk = idx >> 3, j = idx & 7;
      int l15 = chunk & 15, quad = (chunk >> 4) & 3, g = chunk >> 6;
      int ks = g % 3, mi = g / 3;
      int o = mi * 16 + l15;
      int k = ks * 32 + quad * 8 + j;
      int i = k & 31, dt = k >> 5;
      wt2[idx] = f2b(t2w[(o * 32 + i) * 3 + dt]);
    }
  }
}

// --------------------------- unified MFMA conv/mix kernel -------------------
template <int MODE>
__global__ __launch_bounds__(256, 2)
void k_mix(const u16* __restrict__ x0, const u16* __restrict__ y1,
           const u16* __restrict__ y2, const u16* __restrict__ wp,
           const float* __restrict__ b0, const float* __restrict__ b1,
           u16* __restrict__ out, int T_in, int T) {
  constexpr int M = (MODE == 1) ? 32 : 64;
  constexpr int K = (MODE == 0) ? 192 : 96;
  constexpr int KS = K / 32;
  constexpr int MT = M / 16;
  constexpr int WCH = ((MT * KS * 64) + 255) & ~255;
  constexpr int XCH = KS * 8 * 65;
  __shared__ __align__(16) u16 lw[WCH * 8];
  __shared__ __align__(16) u16 lx[XCH * 8];

  const int tid = threadIdx.x;
  const int lane = tid & 63, wave = tid >> 6;
  const int quad = lane >> 4, l15 = lane & 15;
  const int n0 = blockIdx.x * 128;
  const int b = blockIdx.y / T, t = blockIdx.y % T;

#pragma unroll
  for (int p = 0; p < WCH / 256; ++p)
    gl_lds16(wp + (size_t)(p * 256 + wave * 64 + lane) * 8,
             &lw[(p * 256 + wave * 64) * 8]);

  const bool guard = (MODE != 1) && (n0 + 128 > 2000);
  for (int p = 0; p < KS; ++p) {
    const int k4 = p * 8 + (tid >> 5);
    const int nloc = (tid & 31) * 4;
    us4 rv[4];
#pragma unroll
    for (int i = 0; i < 4; ++i) {
      const int k = k4 * 4 + i;
      const u16* rp;
      if (MODE == 0) {
        rp = x0 + (size_t)((b * 64 + (k & 63)) * T_in + t + (k >> 6)) * 2000;
      } else if (MODE == 1) {
        const u16* base = (k < 32) ? x0 : ((k < 64) ? y1 : y2);
        rp = base + (size_t)((b * 32 + (k & 31)) * T_in + t) * 2048;
      } else {
        rp = x0 + (size_t)((b * 32 + (k & 31)) * T_in + t + (k >> 5)) * 2000;
      }
      rv[i] = guard ? load4_guard(rp + n0 + nloc, n0 + nloc)
                    : *(const us4*)(rp + n0 + nloc);
    }
    const int quadw = (k4 >> 1) & 3;
    const int j0 = (k4 & 1) * 4;
#pragma unroll
    for (int i = 0; i < 4; ++i) {
      const int nn = nloc + i;
      const int chunk = (p * 8 + (nn >> 4)) * 65 + quadw * 16 + (nn & 15);
      us4 wv;
      wv.v[0] = rv[0].v[i]; wv.v[1] = rv[1].v[i];
      wv.v[2] = rv[2].v[i]; wv.v[3] = rv[3].v[i];
      *(us4*)&lx[chunk * 8 + j0] = wv;
    }
  }
  asm volatile("s_waitcnt vmcnt(0)" ::: "memory");
  __syncthreads();

  floatx4 acc[MT][2] = {};
#pragma unroll
  for (int ks = 0; ks < KS; ++ks) {
    short8 bfr[2], afr[MT];
#pragma unroll
    for (int nj = 0; nj < 2; ++nj)
      bfr[nj] = *(const short8*)&lx[(((ks * 8 + wave * 2 + nj) * 65) + lane) * 8];
#pragma unroll
    for (int mi = 0; mi < MT; ++mi)
      afr[mi] = *(const short8*)&lw[((mi * KS + ks) * 64 + lane) * 8];
#pragma unroll
    for (int mi = 0; mi < MT; ++mi)
#pragma unroll
      for (int nj = 0; nj < 2; ++nj)
        acc[mi][nj] = __builtin_amdgcn_mfma_f32_16x16x32_bf16(
            afr[mi], bfr[nj], acc[mi][nj], 0, 0, 0);
  }

#pragma unroll
  for (int nj = 0; nj < 2; ++nj) {
    const int nblk = wave * 2 + nj;
    const int n = n0 + nblk * 16 + l15;
    if (MODE == 0) {
#pragma unroll
      for (int mi = 0; mi < 2; ++mi)
#pragma unroll
        for (int r = 0; r < 4; ++r) {
          const int i = mi * 16 + quad * 4 + r;
          const float sv = acc[mi][nj][r] + b0[i] + b1[i];
          const float gt = acc[mi + 2][nj][r] + b0[32 + i];
          const float val = sv / (1.f + __expf(-gt));
          out[(size_t)((b * 32 + i) * T + t) * 2048 + n] = f2b(val);
        }
    } else if (MODE == 1) {
#pragma unroll
      for (int mi = 0; mi < MT; ++mi)
#pragma unroll
        for (int r = 0; r < 4; ++r) {
          const int o = mi * 16 + quad * 4 + r;
          const int rc = nblk * 65 + ((o >> 3) & 3) * 16 + l15;
          float v = acc[mi][nj][r] + b0[o] + b2f(lx[rc * 8 + (o & 7)]);
          if (n < 2000)
            out[(size_t)((b * 32 + o) * T + t) * 2000 + n] = f2b(fmaxf(v, 0.f));
        }
    } else {
#pragma unroll
      for (int mi = 0; mi < MT; ++mi)
#pragma unroll
        for (int r = 0; r < 4; ++r) {
          const int o = mi * 16 + quad * 4 + r;
          float v = acc[mi][nj][r] + b0[o];
          if (o < 32) {
            const int rc = (16 + nblk) * 65 + ((o >> 3) & 3) * 16 + l15;
            v += b2f(lx[rc * 8 + (o & 7)]);
          }
          if (n < 2000)
            out[(size_t)((b * 64 + o) * T + t) * 2000 + n] = f2b(fmaxf(v, 0.f));
        }
    }
  }
}

// --------------------------- bf16 MFMA GEMM (C = A * Bt^T) ------------------
// 128 threads, block tile 128x128, wave-tile 64m x 128n (32 MFMA / 12 reads).
// R4: sigma-swizzle LDS (chunk q of row r at pos (q+sig(r&15))&3, sig(x)=
// (x+(x>>2))&3 -> 2-way bank aliasing = free) + explicit double buffer:
// per K-step {vmcnt(own prev loads, already landed) ; s_barrier ; DMA next
// tile into other buffer ; ds_read ; MFMA}. Wave0 stages A, wave1 stages B.
__global__ __launch_bounds__(128, 2)
void k_gemm(const u16* __restrict__ A, const u16* __restrict__ Bt,
            u16* __restrict__ C) {
  constexpr int K = 2048;
  __shared__ u16 As[2][128 * 32];
  __shared__ u16 Bs[2][128 * 32];
  const int tid = threadIdx.x;
  const int lane = tid & 63, wave = tid >> 6;
  const int m0 = blockIdx.y * 128, n0 = blockIdx.x * 128;
  const int quad = lane >> 4, l15 = lane & 15;

  // staging source: instr p, lane l -> tile row p*16+(l>>2), LDS pos l&3,
  // global chunk q = (pos - sig(row)) & 3  (rotation within the 64B segment)
  const int lrow = lane >> 2;
  const int sig = (lrow + (lrow >> 2)) & 3;
  const int q = ((lane & 3) - sig) & 3;
  const u16* g = ((wave == 0) ? (A + (size_t)(m0 + lrow) * K)
                              : (Bt + (size_t)(n0 + lrow) * K)) + q * 8;
  u16* lb0 = (wave == 0) ? As[0] : Bs[0];
  u16* lb1 = (wave == 0) ? As[1] : Bs[1];

  // fragment read addresses (sigma-swizzled)
  const int sigr = (l15 + (l15 >> 2)) & 3;
  const int cofs = ((quad + sigr) & 3) * 8;

  floatx4 acc[4][8] = {};

  // prologue: tile 0 -> buffer 0
#pragma unroll
  for (int p = 0; p < 8; ++p)
    gl_lds16(g + (size_t)p * 16 * K, lb0 + p * 512);

  int cur = 0;
  for (int k0 = 0; k0 < K; k0 += 32) {
    asm volatile("s_waitcnt vmcnt(0)" ::: "memory");  // own prev-tile DMAs done
    asm volatile("s_barrier" ::: "memory");           // all waves: DMAs done,
                                                      // prev-iter reads retired
    if (k0 + 32 < K) {
      const u16* gn = g + (k0 + 32);
      u16* ldst = cur ? lb0 : lb1;
#pragma unroll
      for (int p = 0; p < 8; ++p)
        gl_lds16(gn + (size_t)p * 16 * K, ldst + p * 512);
    }
    const u16* as = As[cur];
    const u16* bs = Bs[cur];
    short8 af[4], bf[8];
#pragma unroll
    for (int mi = 0; mi < 4; ++mi)
      af[mi] = *(const short8*)&as[(wave * 64 + mi * 16 + l15) * 32 + cofs];
#pragma unroll
    for (int ni = 0; ni < 8; ++ni)
      bf[ni] = *(const short8*)&bs[(ni * 16 + l15) * 32 + cofs];
#pragma unroll
    for (int mi = 0; mi < 4; ++mi)
#pragma unroll
      for (int ni = 0; ni < 8; ++ni)
        acc[mi][ni] = __builtin_amdgcn_mfma_f32_16x16x32_bf16(
            af[mi], bf[ni], acc[mi][ni], 0, 0, 0);
    cur ^= 1;
  }

#pragma unroll
  for (int mi = 0; mi < 4; ++mi) {
#pragma unroll
    for (int ni = 0; ni < 8; ++ni) {
      const int row = m0 + wave * 64 + mi * 16 + quad * 4;
      const int col = n0 + ni * 16 + l15;
#pragma unroll
      for (int r = 0; r < 4; ++r)
        C[(size_t)(row + r) * K + col] = f2b(acc[mi][ni][r]);
    }
  }
}

// --------------------------- LayerNorm --------------------------------------

__global__ void k_lnpart(const u16* __restrict__ h, float* __restrict__ part, int T) {
  const int bt = blockIdx.x, cg = blockIdx.y;
  const int b = bt / T, t = bt % T;
  const int tid = threadIdx.x;
  float s = 0.f, ss = 0.f;
  for (int c = cg * 8; c < cg * 8 + 8; ++c) {
    const u16* row = h + (size_t)((b * 64 + c) * T + t) * 2000;
    for (int n = tid * 4; n < 2000; n += 1024) {
      const us4 hv = *(const us4*)(row + n);
#pragma unroll
      for (int i = 0; i < 4; ++i) {
        const float v = b2f(hv.v[i]);
        s += v; ss += v * v;
      }
    }
  }
  __shared__ float r1[256], r2[256];
  r1[tid] = s; r2[tid] = ss;
  __syncthreads();
  for (int st = 128; st > 0; st >>= 1) {
    if (tid < st) { r1[tid] += r1[tid + st]; r2[tid] += r2[tid + st]; }
    __syncthreads();
  }
  if (tid == 0) {
    part[(bt * 8 + cg) * 2 + 0] = r1[0];
    part[(bt * 8 + cg) * 2 + 1] = r2[0];
  }
}

__global__ void k_lnfin(const float* __restrict__ part, float* __restrict__ stats,
                        int BT) {
  const int i = blockIdx.x * 256 + threadIdx.x;
  if (i >= BT) return;
  float s = 0.f, ss = 0.f;
  for (int g = 0; g < 8; ++g) {
    s  += part[(i * 8 + g) * 2 + 0];
    ss += part[(i * 8 + g) * 2 + 1];
  }
  const float inv = 1.f / 128000.f;
  const float mu = s * inv;
  const float var = ss * inv - mu * mu;
  stats[i * 2] = mu;
  stats[i * 2 + 1] = rsqrtf(var + 1e-5f);
}

// transpose gamma/beta [2000,64] -> [64,2048] (pad zeros)
__global__ void k_lngbT(const float* __restrict__ gw, const float* __restrict__ gb,
                        float* __restrict__ gwT, float* __restrict__ gbT) {
  const int n = blockIdx.x * 256 + threadIdx.x;
  const int c = blockIdx.y;
  float vw = 0.f, vb = 0.f;
  if (n < 2000) {
    vw = gw[(size_t)n * 64 + c];
    vb = gb[(size_t)n * 64 + c];
  }
  gwT[(size_t)c * 2048 + n] = vw;
  gbT[(size_t)c * 2048 + n] = vb;
}

__global__ void k_lnapply(u16* __restrict__ h, const float* __restrict__ stats,
                          const float* __restrict__ gwT, const float* __restrict__ gbT,
                          float* __restrict__ outf, int T, int write_f32) {
  const int n = blockIdx.x * 1024 + threadIdx.x * 4;
  if (n >= 2000) return;  // 2000%4==0: full chunks only
  int by = blockIdx.y;
  const int t = by % T; by /= T;
  const int c = by & 63;
  const int b = by >> 6;
  const int bt = b * T + t;
  const float mu = stats[bt * 2], rs = stats[bt * 2 + 1];
  const size_t row = (size_t)((b * 64 + c) * T + t) * 2000 + n;
  const us4 hv = *(const us4*)(h + row);
  const float4 w4 = *(const float4*)(gwT + (size_t)c * 2048 + n);
  const float4 b4 = *(const float4*)(gbT + (size_t)c * 2048 + n);
  const float o0 = (b2f(hv.v[0]) - mu) * rs * w4.x + b4.x;
  const float o1 = (b2f(hv.v[1]) - mu) * rs * w4.y + b4.y;
  const float o2 = (b2f(hv.v[2]) - mu) * rs * w4.z + b4.z;
  const float o3 = (b2f(hv.v[3]) - mu) * rs * w4.w + b4.w;
  if (write_f32) {
    *(float4*)(outf + row) = make_float4(o0, o1, o2, o3);
  } else {
    us4 r;
    r.v[0] = f2b(o0); r.v[1] = f2b(o1); r.v[2] = f2b(o2); r.v[3] = f2b(o3);
    *(us4*)(h + row) = r;
  }
}

// --------------------------- launch -----------------------------------------

extern "C" void kernel_launch(void* const* d_in, const int* in_sizes, int n_in,
                              void* d_out, int out_size, void* d_ws, size_t ws_size,
                              hipStream_t stream) {
  const float* x     = (const float*)d_in[0];
  const float* graph = (const float*)d_in[1];
  const float* in_w  = (const float*)d_in[2];
  const float* in_b  = (const float*)d_in[3];

  char* ws = (char*)d_ws;
  size_t off = 0;
  auto alloc = [&](size_t bytes) -> void* {
    void* p = ws + off;
    off += (bytes + 255) & ~(size_t)255;
    return p;
  };
  float* dd    = (float*)alloc(2048 * 4);
  float* stats = (float*)alloc(16 * 12 * 2 * 4);
  float* part  = (float*)alloc(16 * 8 * 8 * 2 * 4);
  float* gwT   = (float*)alloc((size_t)64 * 2048 * 4);
  float* gbT   = (float*)alloc((size_t)64 * 2048 * 4);
  u16* wpg  = (u16*)alloc((size_t)1536 * 8 * 2);
  u16* wpt  = (u16*)alloc((size_t)512 * 8 * 2);
  u16* wp2  = (u16*)alloc((size_t)768 * 8 * 2);
  u16* L    = (u16*)alloc((size_t)2048 * 2048 * 2);
  u16* h0   = (u16*)alloc((size_t)16 * 64 * 12 * 2000 * 2);
  u16* Xp   = (u16*)alloc((size_t)5120 * 2048 * 2);
  u16* Y1   = (u16*)alloc((size_t)5120 * 2048 * 2);
  u16* Y2   = (u16*)alloc((size_t)5120 * 2048 * 2);
  u16* sbuf = (u16*)alloc((size_t)16 * 32 * 10 * 2000 * 2);
  u16* h1   = (u16*)alloc((size_t)16 * 64 * 8 * 2000 * 2);
  u16* h2   = h0;  // reuse: h0 dead after block-1 GLU
  if (off > ws_size) return;

  k_deg<<<dim3(2000), dim3(256), 0, stream>>>(graph, dd);
  k_lap<<<dim3(2, 2048), dim3(256), 0, stream>>>(graph, dd, L);
  k_inconv<<<dim3(2, 192), dim3(256), 0, stream>>>(x, in_w, in_b, h0);

  for (int blk = 0; blk < 2; ++blk) {
    const int base = 4 + blk * 10;
    const float* t1w = (const float*)d_in[base + 0];
    const float* t1b = (const float*)d_in[base + 1];
    const float* aw  = (const float*)d_in[base + 2];
    const float* ab  = (const float*)d_in[base + 3];
    const float* th  = (const float*)d_in[base + 4];
    const float* sb  = (const float*)d_in[base + 5];
    const float* t2w = (const float*)d_in[base + 6];
    const float* t2b = (const float*)d_in[base + 7];
    const float* lng = (const float*)d_in[base + 8];
    const float* lnb = (const float*)d_in[base + 9];

    const int T_in = (blk == 0) ? 12 : 8;
    const int T_g  = T_in - 2;  // 10 / 6
    const int T_o  = T_g - 2;   // 8 / 4
    const u16* hin = (blk == 0) ? h0 : h1;
    u16* hout      = (blk == 0) ? h1 : h2;
    const int M = 16 * 32 * T_g;  // 5120 / 3072

    k_wpack<<<dim3(3), dim3(256), 0, stream>>>(t1w, aw, th, t2w, wpg, wpt, wp2);
    k_lngbT<<<dim3(8, 64), dim3(256), 0, stream>>>(lng, lnb, gwT, gbT);
    k_mix<0><<<dim3(16, 16 * T_g), dim3(256), 0, stream>>>(
        hin, nullptr, nullptr, wpg, t1b, ab, Xp, T_in, T_g);
    k_gemm<<<dim3(16, M / 128), dim3(128), 0, stream>>>(Xp, L, Y1);
    k_gemm<<<dim3(16, M / 128), dim3(128), 0, stream>>>(Y1, L, Y2);
    k_mix<1><<<dim3(16, 16 * T_g), dim3(256), 0, stream>>>(
        Xp, Y1, Y2, wpt, sb, nullptr, sbuf, T_g, T_g);
    k_mix<2><<<dim3(16, 16 * T_o), dim3(256), 0, stream>>>(
        sbuf, nullptr, nullptr, wp2, t2b, nullptr, hout, T_g, T_o);
    k_lnpart<<<dim3(16 * T_o, 8), dim3(256), 0, stream>>>(hout, part, T_o);
    k_lnfin<<<dim3(1), dim3(256), 0, stream>>>(part, stats, 16 * T_o);
    k_lnapply<<<dim3(2, 16 * 64 * T_o), dim3(256), 0, stream>>>(
        hout, stats, gwT, gbT, (float*)d_out, T_o, blk);
  }
}